// Round 17
// baseline (601.871 us; speedup 1.0000x reference)
//
#include <hip/hip_runtime.h>

#define DI __device__ __forceinline__

typedef __attribute__((ext_vector_type(4))) float f32x4;
typedef __attribute__((ext_vector_type(8))) short s16x8;
typedef __attribute__((ext_vector_type(4))) short s16x4;
typedef unsigned short u16;

#define AS_G(p) ((const __attribute__((address_space(1))) void*)(p))
#define AS_L(p) ((__attribute__((address_space(3))) void*)(p))

DI short f2bf(float f) {
  union { float f; unsigned u; } v; v.f = f;
  unsigned r = v.u + 0x7FFFu + ((v.u >> 16) & 1u);
  return (short)(r >> 16);
}
DI float bf2f(short h) {
  union { unsigned u; float f; } v; v.u = ((unsigned)(u16)h) << 16; return v.f;
}

#define MFMA(a, b, c) __builtin_amdgcn_mfma_f32_16x16x32_bf16((a), (b), (c), 0, 0, 0)

// ---------------------------------------------------------------------------
// K0: cast weights fp32 -> bf16
__global__ void cast_weights_kernel(const float* __restrict__ wqkv, u16* __restrict__ wqkv_bf,
                                    const float* __restrict__ wout, u16* __restrict__ wout_bf) {
  const int n1 = 1536 * 512 / 4, n2 = 512 * 512 / 4;
  for (int c = blockIdx.x * blockDim.x + threadIdx.x; c < n1 + n2; c += gridDim.x * blockDim.x) {
    const float4* src; u16* dst; int idx;
    if (c < n1) { src = (const float4*)wqkv; dst = wqkv_bf; idx = c; }
    else        { src = (const float4*)wout; dst = wout_bf; idx = c - n1; }
    float4 v = src[idx];
    s16x4 o;
    o[0] = f2bf(v.x); o[1] = f2bf(v.y); o[2] = f2bf(v.z); o[3] = f2bf(v.w);
    *(s16x4*)(dst + (long)idx * 4) = o;
  }
}

// ---------------------------------------------------------------------------
// Tiled transpose (64x64 tiles). out[col][row] = in[row][col], cast to bf16.
template<bool IN_F32>
__global__ __launch_bounds__(256)
void transpose_kernel(const void* __restrict__ in, u16* __restrict__ out,
                      int in_rstride, int out_rstride, long plane_in, long plane_out) {
  __shared__ __align__(16) u16 t[64][72];
  const int tid = threadIdx.x;
  const long bi = (long)blockIdx.z * plane_in;
  const long bo = (long)blockIdx.z * plane_out;
  const int r0 = blockIdx.y * 64, c0 = blockIdx.x * 64;
#pragma unroll
  for (int i = 0; i < 4; ++i) {
    int c = tid + i * 256;
    int row = c >> 4, c4 = c & 15;
    s16x4 pk;
    if (IN_F32) {
      const float4 v = *(const float4*)((const float*)in + bi + (long)(r0 + row) * in_rstride + c0 + c4 * 4);
      pk[0] = f2bf(v.x); pk[1] = f2bf(v.y); pk[2] = f2bf(v.z); pk[3] = f2bf(v.w);
    } else {
      pk = *(const s16x4*)((const u16*)in + bi + (long)(r0 + row) * in_rstride + c0 + c4 * 4);
    }
    *(s16x4*)&t[row][c4 * 4] = pk;
  }
  __syncthreads();
#pragma unroll
  for (int i = 0; i < 2; ++i) {
    int c = tid + i * 256;
    int orow = c >> 3, u = c & 7;
    s16x8 pk;
#pragma unroll
    for (int j = 0; j < 8; ++j) pk[j] = (short)t[u * 8 + j][orow];
    *(s16x8*)(out + bo + (long)(c0 + orow) * out_rstride + r0 + u * 8) = pk;
  }
}

// ---------------------------------------------------------------------------
// GEMM (FROZEN at R4-best, 127 us): D[m][n] = sum_k A[m][k] * B_T[n][k]
// tile 128x128, BK=64, 4 waves (2x2), 4x4 frags. 2-phase pipeline: dbuf LDS
// (2x32KB), stage(k+1) issued before compute(k), ONE barrier per K-step.
// global_load_lds w=16, linear LDS dest, XOR-swizzle on global src.
// Epilogues via LDS for coalesced 256B/512B stores.
// EPI 0 v-branch DUAL-STORES v_buf[c][h][w] (coalesced) AND vT[c][w][h]
// (2B scatter, stride 256B — L3-absorbed per R14 evidence), replacing the
// separate vT transpose kernel. Block's p-range = one image row: h = n0/128.
template<int EPI>
__global__ __launch_bounds__(256, 2)
void gemm_kernel(const u16* __restrict__ A, const u16* __restrict__ B,
                 const float* __restrict__ bias,
                 u16* __restrict__ out_qk, u16* __restrict__ out_v,
                 u16* __restrict__ out_vt, float* __restrict__ out_f) {
  __shared__ __align__(16) u16 sAB[2][16384];  // [buf][As 8192 | Bs 8192] = 64 KB
  const int tid = threadIdx.x;
  const int lane = tid & 63, wid = tid >> 6;
  const int l15 = lane & 15, g4 = lane >> 4;
  const int wr = wid >> 1, wc = wid & 1;
  const int m0 = blockIdx.y * 128, n0 = blockIdx.x * 128;
  const int z = blockIdx.z;
  const u16* Bp = B + (long)z * 8388608;

  f32x4 acc[4][4];
#pragma unroll
  for (int i = 0; i < 4; ++i)
#pragma unroll
    for (int j = 0; j < 4; ++j) { f32x4 z4 = {0.f, 0.f, 0.f, 0.f}; acc[i][j] = z4; }

  const int srow = wid * 32 + (lane >> 3);
  const int su = lane & 7;
  auto stage = [&](int kt, int buf) {
    u16* As = sAB[buf];
    u16* Bs = sAB[buf] + 8192;
#pragma unroll
    for (int i = 0; i < 4; ++i) {
      int row = srow + i * 8;
      int ksw = (su ^ (row & 7)) * 8;
      __builtin_amdgcn_global_load_lds(AS_G(A + (long)(m0 + row) * 512 + kt * 64 + ksw),
                                       AS_L(As + wid * 2048 + i * 512), 16, 0, 0);
    }
#pragma unroll
    for (int i = 0; i < 4; ++i) {
      int row = srow + i * 8;
      int ksw = (su ^ (row & 7)) * 8;
      __builtin_amdgcn_global_load_lds(AS_G(Bp + (long)(n0 + row) * 512 + kt * 64 + ksw),
                                       AS_L(Bs + wid * 2048 + i * 512), 16, 0, 0);
    }
  };

  stage(0, 0);
  __syncthreads();
  int cur = 0;
  for (int kt = 0; kt < 8; ++kt) {
    if (kt < 7) stage(kt + 1, cur ^ 1);  // async; drained by barrier below
    const u16* As = sAB[cur];
    const u16* Bs = sAB[cur] + 8192;
#pragma unroll
    for (int ks = 0; ks < 2; ++ks) {
      s16x8 af[4], bfr[4];
#pragma unroll
      for (int mi = 0; mi < 4; ++mi) {
        int row = (wr * 4 + mi) * 16 + l15;
        af[mi] = *(const s16x8*)(As + row * 64 + (((ks * 4 + g4) ^ (row & 7)) * 8));
      }
#pragma unroll
      for (int ni = 0; ni < 4; ++ni) {
        int row = (wc * 4 + ni) * 16 + l15;
        bfr[ni] = *(const s16x8*)(Bs + row * 64 + (((ks * 4 + g4) ^ (row & 7)) * 8));
      }
#pragma unroll
      for (int mi = 0; mi < 4; ++mi)
#pragma unroll
        for (int ni = 0; ni < 4; ++ni)
          acc[mi][ni] = MFMA(af[mi], bfr[ni], acc[mi][ni]);
    }
    __syncthreads();
    cur ^= 1;
  }

  // ---- epilogue via LDS (sAB reused; K-loop fully drained by last barrier)
  u16* tile = (u16*)sAB;        // [128][136] u16
  float* tilef = (float*)sAB;   // [64][136] f32 for EPI 1

  if (EPI == 0) {
    u16* qk_b = out_qk + (long)z * 16777216;
    u16* v_b  = out_v + (long)z * 8388608;
    if (m0 < 1024) {  // q,k: tile[p_local][o_local], rows = p
#pragma unroll
      for (int mi = 0; mi < 4; ++mi) {
        int ol = (wr * 4 + mi) * 16 + 4 * g4;
        int o0 = m0 + ol;
        float b0 = bias[o0], b1 = bias[o0 + 1], b2 = bias[o0 + 2], b3 = bias[o0 + 3];
#pragma unroll
        for (int ni = 0; ni < 4; ++ni) {
          int pl = (wc * 4 + ni) * 16 + l15;
          s16x4 pk;
          pk[0] = f2bf(acc[mi][ni][0] + b0);
          pk[1] = f2bf(acc[mi][ni][1] + b1);
          pk[2] = f2bf(acc[mi][ni][2] + b2);
          pk[3] = f2bf(acc[mi][ni][3] + b3);
          *(s16x4*)(tile + pl * 136 + ol) = pk;
        }
      }
      __syncthreads();
#pragma unroll
      for (int i = 0; i < 8; ++i) {
        int row = i * 16 + (tid >> 4);
        int c8 = (tid & 15) * 8;
        s16x8 vr = *(const s16x8*)(tile + row * 136 + c8);
        *(s16x8*)(qk_b + (long)(n0 + row) * 1024 + m0 + c8) = vr;
      }
    } else {  // v: tile[c_local][p_local], rows = c
#pragma unroll
      for (int mi = 0; mi < 4; ++mi) {
        int cl = (wr * 4 + mi) * 16 + 4 * g4;
        int o0 = m0 + cl;
#pragma unroll
        for (int ni = 0; ni < 4; ++ni) {
          int pl = (wc * 4 + ni) * 16 + l15;
#pragma unroll
          for (int r = 0; r < 4; ++r)
            tile[(cl + r) * 136 + pl] = (u16)f2bf(acc[mi][ni][r] + bias[o0 + r]);
        }
      }
      __syncthreads();
      u16* vt_b = out_vt + (long)z * 8388608;
      const int h0 = n0 >> 7;     // this block's p-range is one image row
#pragma unroll
      for (int i = 0; i < 8; ++i) {
        int row = i * 16 + (tid >> 4);     // c_local
        int c8 = (tid & 15) * 8;           // w base
        s16x8 vr = *(const s16x8*)(tile + row * 136 + c8);
        *(s16x8*)(v_b + (long)(m0 - 1024 + row) * 16384 + n0 + c8) = vr;
        long vtbase = (long)(m0 - 1024 + row) * 16384 + h0;
#pragma unroll
        for (int j = 0; j < 8; ++j)
          vt_b[vtbase + (long)(c8 + j) * 128] = (u16)vr[j];
      }
    }
  } else {
    float* of = out_f + (long)z * 8388608;
#pragma unroll
    for (int pass = 0; pass < 2; ++pass) {
      if (pass) __syncthreads();
      if (wr == pass) {
#pragma unroll
        for (int mi = 0; mi < 4; ++mi) {
          int ol = (wr * 4 + mi) * 16 + 4 * g4;
          int o0 = m0 + ol;
          float bb[4] = {bias[o0], bias[o0 + 1], bias[o0 + 2], bias[o0 + 3]};
#pragma unroll
          for (int ni = 0; ni < 4; ++ni) {
            int pl = (wc * 4 + ni) * 16 + l15;
#pragma unroll
            for (int r = 0; r < 4; ++r)
              tilef[(ol - pass * 64 + r) * 136 + pl] = acc[mi][ni][r] + bb[r];
          }
        }
      }
      __syncthreads();
#pragma unroll
      for (int i = 0; i < 8; ++i) {
        int row = i * 8 + (tid >> 5);
        int c4 = (tid & 31) * 4;
        f32x4 vr = *(const f32x4*)(tilef + row * 136 + c4);
        *(f32x4*)(of + (long)(m0 + pass * 64 + row) * 16384 + n0 + c4) = vr;
      }
    }
  }
}

// ---------------------------------------------------------------------------
// Axial attention, one (batch, head, line) per workgroup, 8 waves.
// MODE 0 (row): lines = h, seq = w, write.  MODE 1 (col): lines = w, seq = h, add.
// Split-stage (q/k drained via vmcnt(2), v in flight under QK^T+softmax);
// coalesced epilogue via f32 LDS tile [128][68].
template<int MODE>
__global__ __launch_bounds__(512, 2)
void attn_kernel(const u16* __restrict__ qk_t_g, const u16* __restrict__ vsrc_g,
                 u16* __restrict__ outp_g) {
  __shared__ __align__(16) u16 smem[24576];  // 48KB
  u16* qT = smem;           // [128][64] chunk-swizzled ^(row&7)
  u16* kT = smem + 8192;    // [128][64]
  u16* vS = smem + 16384;   // [64][128] chunk-swizzled ^(row&15)
  u16* P  = smem;           // [128][128] aliases qT+kT, swizzled ^(w&15)
  float* Tf = (float*)smem; // [128][68] f32 epilogue tile (34816 B), after PV

  const int tid = threadIdx.x;
  const int lane = tid & 63, wid = tid >> 6;
  const int l15 = lane & 15, g4 = lane >> 4;
  const int b = blockIdx.x >> 10;
  const int gidx = blockIdx.x & 1023;
  const int n = gidx >> 7, pos = gidx & 127;

  const u16* qk_t = qk_t_g + (long)b * 16777216;
  const u16* vsrc = vsrc_g + (long)b * 8388608;
  u16* outp = outp_g + (long)b * 8388608;

  long q_base, q_rstride;
  if (MODE == 0) { q_base = (long)pos * 128 * 1024 + n * 64; q_rstride = 1024; }
  else           { q_base = (long)pos * 1024 + n * 64;       q_rstride = 128 * 1024; }
  const long v_base = (long)n * 64 * 16384 + (long)pos * 128;

  // stage q/k first (4 units of 1KB per wave), then v (2 units per wave);
  // vmcnt(2) drains exactly the q/k loads (FIFO), v stays in flight and is
  // drained by the first __syncthreads (after softmax) before PV needs it.
#pragma unroll
  for (int j = 0; j < 4; ++j) {
    int t = wid * 4 + j;          // 0..31: qT / kT units
    int which = t >> 4;
    int tt = t & 15;
    int row = tt * 8 + (lane >> 3);
    int u = lane & 7;
    const u16* src = qk_t + q_base + which * 512 + (long)row * q_rstride + ((u ^ (row & 7)) * 8);
    __builtin_amdgcn_global_load_lds(AS_G(src), AS_L(smem + t * 512), 16, 0, 0);
  }
#pragma unroll
  for (int j = 0; j < 2; ++j) {
    int tt = wid * 2 + j;         // 0..15: vS units
    int row = tt * 4 + (lane >> 4);
    int u = lane & 15;
    const u16* src = vsrc + v_base + (long)row * 16384 + ((u ^ (row & 15)) * 8);
    __builtin_amdgcn_global_load_lds(AS_G(src), AS_L(smem + (32 + tt) * 512), 16, 0, 0);
  }
  asm volatile("s_waitcnt vmcnt(2)" ::: "memory");  // q/k landed; v in flight
  __builtin_amdgcn_s_barrier();
  __builtin_amdgcn_sched_barrier(0);

  // QK^T: wave = m-tile (16 score rows per wave) so each row stays in-wave
  f32x4 acc[8];
#pragma unroll
  for (int nt = 0; nt < 8; ++nt) { f32x4 zz = {0.f, 0.f, 0.f, 0.f}; acc[nt] = zz; }
  s16x8 aq[2];
  {
    int row = wid * 16 + l15;
#pragma unroll
    for (int ks = 0; ks < 2; ++ks)
      aq[ks] = *(const s16x8*)(qT + row * 64 + (((ks * 4 + g4) ^ (row & 7)) * 8));
  }
  __builtin_amdgcn_s_setprio(1);
#pragma unroll
  for (int nt = 0; nt < 8; ++nt) {
    int rowk = nt * 16 + l15;
#pragma unroll
    for (int ks = 0; ks < 2; ++ks) {
      s16x8 bk = *(const s16x8*)(kT + rowk * 64 + (((ks * 4 + g4) ^ (rowk & 7)) * 8));
      acc[nt] = MFMA(aq[ks], bk, acc[nt]);
    }
  }
  __builtin_amdgcn_s_setprio(0);

  // in-register softmax: row w = wid*16 + 4*g4 + r, cols u = nt*16 + l15
#pragma unroll
  for (int r = 0; r < 4; ++r) {
    float m = -1e30f;
#pragma unroll
    for (int nt = 0; nt < 8; ++nt) m = fmaxf(m, acc[nt][r]);
    m = fmaxf(m, __shfl_xor(m, 1));
    m = fmaxf(m, __shfl_xor(m, 2));
    m = fmaxf(m, __shfl_xor(m, 4));
    m = fmaxf(m, __shfl_xor(m, 8));
    float s = 0.f;
#pragma unroll
    for (int nt = 0; nt < 8; ++nt) {
      float e = __expf((acc[nt][r] - m) * 0.125f);
      acc[nt][r] = e; s += e;
    }
    s += __shfl_xor(s, 1); s += __shfl_xor(s, 2);
    s += __shfl_xor(s, 4); s += __shfl_xor(s, 8);
    float rinv = 1.0f / s;
#pragma unroll
    for (int nt = 0; nt < 8; ++nt) acc[nt][r] *= rinv;
  }
  __syncthreads();  // q/k reads done + implicit vmcnt(0) drains v stage

  // write P[w][u] bf16, swizzled
#pragma unroll
  for (int nt = 0; nt < 8; ++nt) {
    int u = nt * 16 + l15;
#pragma unroll
    for (int r = 0; r < 4; ++r) {
      int w = wid * 16 + 4 * g4 + r;
      int ch = (u >> 3) ^ (w & 15);
      P[w * 128 + ch * 8 + (u & 7)] = (u16)f2bf(acc[nt][r]);
    }
  }
  __syncthreads();

  // PV: D[m=d][n=w] = sum_u V[d][u] * P[w][u];  A=V, B=P (both natural-contig)
  const int mw = wid >> 2, nw = wid & 3;
  f32x4 pacc[2][2];
#pragma unroll
  for (int mi = 0; mi < 2; ++mi)
#pragma unroll
    for (int ni = 0; ni < 2; ++ni) { f32x4 zz = {0.f, 0.f, 0.f, 0.f}; pacc[mi][ni] = zz; }
  __builtin_amdgcn_s_setprio(1);
#pragma unroll
  for (int ks = 0; ks < 4; ++ks) {
    s16x8 av[2], bp[2];
#pragma unroll
    for (int mi = 0; mi < 2; ++mi) {
      int d = (mw * 2 + mi) * 16 + l15;
      av[mi] = *(const s16x8*)(vS + d * 128 + (((ks * 4 + g4) ^ (d & 15)) * 8));
    }
#pragma unroll
    for (int ni = 0; ni < 2; ++ni) {
      int w = (nw * 2 + ni) * 16 + l15;
      bp[ni] = *(const s16x8*)(P + w * 128 + (((ks * 4 + g4) ^ (w & 15)) * 8));
    }
#pragma unroll
    for (int mi = 0; mi < 2; ++mi)
#pragma unroll
      for (int ni = 0; ni < 2; ++ni)
        pacc[mi][ni] = MFMA(av[mi], bp[ni], pacc[mi][ni]);
  }
  __builtin_amdgcn_s_setprio(0);
  __syncthreads();  // all reads of P/vS done; smem free for epilogue tile

  // epilogue: pacc -> Tf[nj(seq)][d] (f32, stride 68), then coalesced stores
#pragma unroll
  for (int mi = 0; mi < 2; ++mi) {
    int d0 = (mw * 2 + mi) * 16 + 4 * g4;
#pragma unroll
    for (int ni = 0; ni < 2; ++ni) {
      int nj = (nw * 2 + ni) * 16 + l15;
      *(f32x4*)(Tf + nj * 68 + d0) = pacc[mi][ni];
    }
  }
  __syncthreads();
  // store pass: 128 rows x 64 u16 (128B/row); 8B per lane, 16 lanes per row
#pragma unroll
  for (int i = 0; i < 4; ++i) {
    int row = (tid >> 4) + i * 32;       // seq index
    int c4 = (tid & 15) * 4;             // d chunk (4 elems)
    f32x4 v4 = *(const f32x4*)(Tf + row * 68 + c4);
    long p = (MODE == 0) ? ((long)pos * 128 + row) : ((long)row * 128 + pos);
    u16* dst = outp + p * 512 + n * 64 + c4;
    s16x4 pk;
    if (MODE == 0) {
#pragma unroll
      for (int r = 0; r < 4; ++r) pk[r] = f2bf(v4[r]);
    } else {
      s16x4 old = *(const s16x4*)dst;
#pragma unroll
      for (int r = 0; r < 4; ++r) pk[r] = f2bf(bf2f(old[r]) + v4[r]);
    }
    *(s16x4*)dst = pk;
  }
}

// ---------------------------------------------------------------------------
extern "C" void kernel_launch(void* const* d_in, const int* in_sizes, int n_in,
                              void* d_out, int out_size, void* d_ws, size_t ws_size,
                              hipStream_t stream) {
  const float* x    = (const float*)d_in[0];
  const float* wqkv = (const float*)d_in[1];
  const float* bqkv = (const float*)d_in[2];
  const float* wout = (const float*)d_in[3];
  const float* bout = (const float*)d_in[4];
  float* out = (float*)d_out;

  char* ws = (char*)d_ws;
  size_t off = 0;
  auto alloc = [&](size_t bytes) { void* p = ws + off; off += (bytes + 255) & ~(size_t)255; return p; };
  u16* wqkv_bf = (u16*)alloc(1536L * 512 * 2);
  u16* wout_bf = (u16*)alloc(512L * 512 * 2);
  u16* xT      = (u16*)alloc(4L * 16384 * 512 * 2);   // [b][p][c]
  u16* qk_t    = (u16*)alloc(4L * 16384 * 1024 * 2);  // [b][p][o] o in 0..1023 (q,k)
  u16* v_buf   = (u16*)alloc(4L * 512 * 16384 * 2);   // [b][c][h][w]
  u16* vT      = (u16*)alloc(4L * 512 * 16384 * 2);   // [b][c][w][h]
  u16* attn_T  = (u16*)alloc(4L * 16384 * 512 * 2);   // [b][p][c]
  // total ws use ~386 MiB (ws = 512 MiB)

  cast_weights_kernel<<<256, 256, 0, stream>>>(wqkv, wqkv_bf, wout, wout_bf);
  // xT[b][p][c] = x[b][c][p]
  transpose_kernel<true><<<dim3(256, 8, 4), 256, 0, stream>>>(
      x, xT, 16384, 512, 512L * 16384, 16384L * 512);
  // qkv projection, all batches; v-epilogue dual-stores v_buf AND vT
  gemm_kernel<0><<<dim3(128, 12, 4), 256, 0, stream>>>(wqkv_bf, xT, bqkv, qk_t, v_buf, vT, nullptr);
  // row attention (write), col attention (add)
  attn_kernel<0><<<dim3(4096), 512, 0, stream>>>(qk_t, v_buf, attn_T);
  attn_kernel<1><<<dim3(4096), 512, 0, stream>>>(qk_t, vT, attn_T);
  // out projection, all batches
  gemm_kernel<1><<<dim3(128, 4, 4), 256, 0, stream>>>(wout_bf, attn_T, bout, nullptr, nullptr, nullptr, out);
}

// Round 18
// 378.295 us; speedup vs baseline: 1.5910x; 1.5910x over previous
//
#include <hip/hip_runtime.h>

#define DI __device__ __forceinline__

typedef __attribute__((ext_vector_type(4))) float f32x4;
typedef __attribute__((ext_vector_type(8))) short s16x8;
typedef __attribute__((ext_vector_type(4))) short s16x4;
typedef unsigned short u16;

#define AS_G(p) ((const __attribute__((address_space(1))) void*)(p))
#define AS_L(p) ((__attribute__((address_space(3))) void*)(p))

DI short f2bf(float f) {
  union { float f; unsigned u; } v; v.f = f;
  unsigned r = v.u + 0x7FFFu + ((v.u >> 16) & 1u);
  return (short)(r >> 16);
}
DI float bf2f(short h) {
  union { unsigned u; float f; } v; v.u = ((unsigned)(u16)h) << 16; return v.f;
}

#define MFMA(a, b, c) __builtin_amdgcn_mfma_f32_16x16x32_bf16((a), (b), (c), 0, 0, 0)

// ---------------------------------------------------------------------------
// K0: cast weights fp32 -> bf16
__global__ void cast_weights_kernel(const float* __restrict__ wqkv, u16* __restrict__ wqkv_bf,
                                    const float* __restrict__ wout, u16* __restrict__ wout_bf) {
  const int n1 = 1536 * 512 / 4, n2 = 512 * 512 / 4;
  for (int c = blockIdx.x * blockDim.x + threadIdx.x; c < n1 + n2; c += gridDim.x * blockDim.x) {
    const float4* src; u16* dst; int idx;
    if (c < n1) { src = (const float4*)wqkv; dst = wqkv_bf; idx = c; }
    else        { src = (const float4*)wout; dst = wout_bf; idx = c - n1; }
    float4 v = src[idx];
    s16x4 o;
    o[0] = f2bf(v.x); o[1] = f2bf(v.y); o[2] = f2bf(v.z); o[3] = f2bf(v.w);
    *(s16x4*)(dst + (long)idx * 4) = o;
  }
}

// ---------------------------------------------------------------------------
// Tiled transpose (64x64 tiles). out[col][row] = in[row][col], cast to bf16.
template<bool IN_F32>
__global__ __launch_bounds__(256)
void transpose_kernel(const void* __restrict__ in, u16* __restrict__ out,
                      int in_rstride, int out_rstride, long plane_in, long plane_out) {
  __shared__ __align__(16) u16 t[64][72];
  const int tid = threadIdx.x;
  const long bi = (long)blockIdx.z * plane_in;
  const long bo = (long)blockIdx.z * plane_out;
  const int r0 = blockIdx.y * 64, c0 = blockIdx.x * 64;
#pragma unroll
  for (int i = 0; i < 4; ++i) {
    int c = tid + i * 256;
    int row = c >> 4, c4 = c & 15;
    s16x4 pk;
    if (IN_F32) {
      const float4 v = *(const float4*)((const float*)in + bi + (long)(r0 + row) * in_rstride + c0 + c4 * 4);
      pk[0] = f2bf(v.x); pk[1] = f2bf(v.y); pk[2] = f2bf(v.z); pk[3] = f2bf(v.w);
    } else {
      pk = *(const s16x4*)((const u16*)in + bi + (long)(r0 + row) * in_rstride + c0 + c4 * 4);
    }
    *(s16x4*)&t[row][c4 * 4] = pk;
  }
  __syncthreads();
#pragma unroll
  for (int i = 0; i < 2; ++i) {
    int c = tid + i * 256;
    int orow = c >> 3, u = c & 7;
    s16x8 pk;
#pragma unroll
    for (int j = 0; j < 8; ++j) pk[j] = (short)t[u * 8 + j][orow];
    *(s16x8*)(out + bo + (long)(c0 + orow) * out_rstride + r0 + u * 8) = pk;
  }
}

// ---------------------------------------------------------------------------
// GEMM (FROZEN at R4-best, 127 us): D[m][n] = sum_k A[m][k] * B_T[n][k]
// tile 128x128, BK=64, 4 waves (2x2), 4x4 frags. 2-phase pipeline: dbuf LDS
// (2x32KB), stage(k+1) issued before compute(k), ONE barrier per K-step.
// global_load_lds w=16, linear LDS dest, XOR-swizzle on global src.
// Epilogues via LDS for coalesced 256B/512B stores.
template<int EPI>
__global__ __launch_bounds__(256, 2)
void gemm_kernel(const u16* __restrict__ A, const u16* __restrict__ B,
                 const float* __restrict__ bias,
                 u16* __restrict__ out_qk, u16* __restrict__ out_v,
                 float* __restrict__ out_f) {
  __shared__ __align__(16) u16 sAB[2][16384];  // [buf][As 8192 | Bs 8192] = 64 KB
  const int tid = threadIdx.x;
  const int lane = tid & 63, wid = tid >> 6;
  const int l15 = lane & 15, g4 = lane >> 4;
  const int wr = wid >> 1, wc = wid & 1;
  const int m0 = blockIdx.y * 128, n0 = blockIdx.x * 128;
  const int z = blockIdx.z;
  const u16* Bp = B + (long)z * 8388608;

  f32x4 acc[4][4];
#pragma unroll
  for (int i = 0; i < 4; ++i)
#pragma unroll
    for (int j = 0; j < 4; ++j) { f32x4 z4 = {0.f, 0.f, 0.f, 0.f}; acc[i][j] = z4; }

  const int srow = wid * 32 + (lane >> 3);
  const int su = lane & 7;
  auto stage = [&](int kt, int buf) {
    u16* As = sAB[buf];
    u16* Bs = sAB[buf] + 8192;
#pragma unroll
    for (int i = 0; i < 4; ++i) {
      int row = srow + i * 8;
      int ksw = (su ^ (row & 7)) * 8;
      __builtin_amdgcn_global_load_lds(AS_G(A + (long)(m0 + row) * 512 + kt * 64 + ksw),
                                       AS_L(As + wid * 2048 + i * 512), 16, 0, 0);
    }
#pragma unroll
    for (int i = 0; i < 4; ++i) {
      int row = srow + i * 8;
      int ksw = (su ^ (row & 7)) * 8;
      __builtin_amdgcn_global_load_lds(AS_G(Bp + (long)(n0 + row) * 512 + kt * 64 + ksw),
                                       AS_L(Bs + wid * 2048 + i * 512), 16, 0, 0);
    }
  };

  stage(0, 0);
  __syncthreads();
  int cur = 0;
  for (int kt = 0; kt < 8; ++kt) {
    if (kt < 7) stage(kt + 1, cur ^ 1);  // async; drained by barrier below
    const u16* As = sAB[cur];
    const u16* Bs = sAB[cur] + 8192;
#pragma unroll
    for (int ks = 0; ks < 2; ++ks) {
      s16x8 af[4], bfr[4];
#pragma unroll
      for (int mi = 0; mi < 4; ++mi) {
        int row = (wr * 4 + mi) * 16 + l15;
        af[mi] = *(const s16x8*)(As + row * 64 + (((ks * 4 + g4) ^ (row & 7)) * 8));
      }
#pragma unroll
      for (int ni = 0; ni < 4; ++ni) {
        int row = (wc * 4 + ni) * 16 + l15;
        bfr[ni] = *(const s16x8*)(Bs + row * 64 + (((ks * 4 + g4) ^ (row & 7)) * 8));
      }
#pragma unroll
      for (int mi = 0; mi < 4; ++mi)
#pragma unroll
        for (int ni = 0; ni < 4; ++ni)
          acc[mi][ni] = MFMA(af[mi], bfr[ni], acc[mi][ni]);
    }
    __syncthreads();
    cur ^= 1;
  }

  // ---- epilogue via LDS (sAB reused; K-loop fully drained by last barrier)
  u16* tile = (u16*)sAB;        // [128][136] u16
  float* tilef = (float*)sAB;   // [64][136] f32 for EPI 1

  if (EPI == 0) {
    u16* qk_b = out_qk + (long)z * 16777216;
    u16* v_b  = out_v + (long)z * 8388608;
    if (m0 < 1024) {  // q,k: tile[p_local][o_local], rows = p
#pragma unroll
      for (int mi = 0; mi < 4; ++mi) {
        int ol = (wr * 4 + mi) * 16 + 4 * g4;
        int o0 = m0 + ol;
        float b0 = bias[o0], b1 = bias[o0 + 1], b2 = bias[o0 + 2], b3 = bias[o0 + 3];
#pragma unroll
        for (int ni = 0; ni < 4; ++ni) {
          int pl = (wc * 4 + ni) * 16 + l15;
          s16x4 pk;
          pk[0] = f2bf(acc[mi][ni][0] + b0);
          pk[1] = f2bf(acc[mi][ni][1] + b1);
          pk[2] = f2bf(acc[mi][ni][2] + b2);
          pk[3] = f2bf(acc[mi][ni][3] + b3);
          *(s16x4*)(tile + pl * 136 + ol) = pk;
        }
      }
      __syncthreads();
#pragma unroll
      for (int i = 0; i < 8; ++i) {
        int row = i * 16 + (tid >> 4);
        int c8 = (tid & 15) * 8;
        s16x8 vr = *(const s16x8*)(tile + row * 136 + c8);
        *(s16x8*)(qk_b + (long)(n0 + row) * 1024 + m0 + c8) = vr;
      }
    } else {  // v: tile[c_local][p_local], rows = c
#pragma unroll
      for (int mi = 0; mi < 4; ++mi) {
        int cl = (wr * 4 + mi) * 16 + 4 * g4;
        int o0 = m0 + cl;
#pragma unroll
        for (int ni = 0; ni < 4; ++ni) {
          int pl = (wc * 4 + ni) * 16 + l15;
#pragma unroll
          for (int r = 0; r < 4; ++r)
            tile[(cl + r) * 136 + pl] = (u16)f2bf(acc[mi][ni][r] + bias[o0 + r]);
        }
      }
      __syncthreads();
#pragma unroll
      for (int i = 0; i < 8; ++i) {
        int row = i * 16 + (tid >> 4);
        int c8 = (tid & 15) * 8;
        s16x8 vr = *(const s16x8*)(tile + row * 136 + c8);
        *(s16x8*)(v_b + (long)(m0 - 1024 + row) * 16384 + n0 + c8) = vr;
      }
    }
  } else {
    float* of = out_f + (long)z * 8388608;
#pragma unroll
    for (int pass = 0; pass < 2; ++pass) {
      if (pass) __syncthreads();
      if (wr == pass) {
#pragma unroll
        for (int mi = 0; mi < 4; ++mi) {
          int ol = (wr * 4 + mi) * 16 + 4 * g4;
          int o0 = m0 + ol;
          float bb[4] = {bias[o0], bias[o0 + 1], bias[o0 + 2], bias[o0 + 3]};
#pragma unroll
          for (int ni = 0; ni < 4; ++ni) {
            int pl = (wc * 4 + ni) * 16 + l15;
#pragma unroll
            for (int r = 0; r < 4; ++r)
              tilef[(ol - pass * 64 + r) * 136 + pl] = acc[mi][ni][r] + bb[r];
          }
        }
      }
      __syncthreads();
#pragma unroll
      for (int i = 0; i < 8; ++i) {
        int row = i * 8 + (tid >> 5);
        int c4 = (tid & 31) * 4;
        f32x4 vr = *(const f32x4*)(tilef + row * 136 + c4);
        *(f32x4*)(of + (long)(m0 + pass * 64 + row) * 16384 + n0 + c4) = vr;
      }
    }
  }
}

// ---------------------------------------------------------------------------
// Axial attention, one (batch, head, line) per workgroup, 8 waves.
// MODE 0 (row): lines = h, seq = w, write.  MODE 1 (col): lines = w, seq = h, add.
// Split-stage (q/k drained via vmcnt(2), v in flight under QK^T+softmax);
// coalesced epilogue via f32 LDS tile [128][68].
template<int MODE>
__global__ __launch_bounds__(512, 2)
void attn_kernel(const u16* __restrict__ qk_t_g, const u16* __restrict__ vsrc_g,
                 u16* __restrict__ outp_g) {
  __shared__ __align__(16) u16 smem[24576];  // 48KB
  u16* qT = smem;           // [128][64] chunk-swizzled ^(row&7)
  u16* kT = smem + 8192;    // [128][64]
  u16* vS = smem + 16384;   // [64][128] chunk-swizzled ^(row&15)
  u16* P  = smem;           // [128][128] aliases qT+kT, swizzled ^(w&15)
  float* Tf = (float*)smem; // [128][68] f32 epilogue tile (34816 B), after PV

  const int tid = threadIdx.x;
  const int lane = tid & 63, wid = tid >> 6;
  const int l15 = lane & 15, g4 = lane >> 4;
  const int b = blockIdx.x >> 10;
  const int gidx = blockIdx.x & 1023;
  const int n = gidx >> 7, pos = gidx & 127;

  const u16* qk_t = qk_t_g + (long)b * 16777216;
  const u16* vsrc = vsrc_g + (long)b * 8388608;
  u16* outp = outp_g + (long)b * 8388608;

  long q_base, q_rstride;
  if (MODE == 0) { q_base = (long)pos * 128 * 1024 + n * 64; q_rstride = 1024; }
  else           { q_base = (long)pos * 1024 + n * 64;       q_rstride = 128 * 1024; }
  const long v_base = (long)n * 64 * 16384 + (long)pos * 128;

  // stage q/k first (4 units of 1KB per wave), then v (2 units per wave);
  // vmcnt(2) drains exactly the q/k loads (FIFO), v stays in flight and is
  // drained by the first __syncthreads (after softmax) before PV needs it.
#pragma unroll
  for (int j = 0; j < 4; ++j) {
    int t = wid * 4 + j;          // 0..31: qT / kT units
    int which = t >> 4;
    int tt = t & 15;
    int row = tt * 8 + (lane >> 3);
    int u = lane & 7;
    const u16* src = qk_t + q_base + which * 512 + (long)row * q_rstride + ((u ^ (row & 7)) * 8);
    __builtin_amdgcn_global_load_lds(AS_G(src), AS_L(smem + t * 512), 16, 0, 0);
  }
#pragma unroll
  for (int j = 0; j < 2; ++j) {
    int tt = wid * 2 + j;         // 0..15: vS units
    int row = tt * 4 + (lane >> 4);
    int u = lane & 15;
    const u16* src = vsrc + v_base + (long)row * 16384 + ((u ^ (row & 15)) * 8);
    __builtin_amdgcn_global_load_lds(AS_G(src), AS_L(smem + (32 + tt) * 512), 16, 0, 0);
  }
  asm volatile("s_waitcnt vmcnt(2)" ::: "memory");  // q/k landed; v in flight
  __builtin_amdgcn_s_barrier();
  __builtin_amdgcn_sched_barrier(0);

  // QK^T: wave = m-tile (16 score rows per wave) so each row stays in-wave
  f32x4 acc[8];
#pragma unroll
  for (int nt = 0; nt < 8; ++nt) { f32x4 zz = {0.f, 0.f, 0.f, 0.f}; acc[nt] = zz; }
  s16x8 aq[2];
  {
    int row = wid * 16 + l15;
#pragma unroll
    for (int ks = 0; ks < 2; ++ks)
      aq[ks] = *(const s16x8*)(qT + row * 64 + (((ks * 4 + g4) ^ (row & 7)) * 8));
  }
  __builtin_amdgcn_s_setprio(1);
#pragma unroll
  for (int nt = 0; nt < 8; ++nt) {
    int rowk = nt * 16 + l15;
#pragma unroll
    for (int ks = 0; ks < 2; ++ks) {
      s16x8 bk = *(const s16x8*)(kT + rowk * 64 + (((ks * 4 + g4) ^ (rowk & 7)) * 8));
      acc[nt] = MFMA(aq[ks], bk, acc[nt]);
    }
  }
  __builtin_amdgcn_s_setprio(0);

  // in-register softmax: row w = wid*16 + 4*g4 + r, cols u = nt*16 + l15
#pragma unroll
  for (int r = 0; r < 4; ++r) {
    float m = -1e30f;
#pragma unroll
    for (int nt = 0; nt < 8; ++nt) m = fmaxf(m, acc[nt][r]);
    m = fmaxf(m, __shfl_xor(m, 1));
    m = fmaxf(m, __shfl_xor(m, 2));
    m = fmaxf(m, __shfl_xor(m, 4));
    m = fmaxf(m, __shfl_xor(m, 8));
    float s = 0.f;
#pragma unroll
    for (int nt = 0; nt < 8; ++nt) {
      float e = __expf((acc[nt][r] - m) * 0.125f);
      acc[nt][r] = e; s += e;
    }
    s += __shfl_xor(s, 1); s += __shfl_xor(s, 2);
    s += __shfl_xor(s, 4); s += __shfl_xor(s, 8);
    float rinv = 1.0f / s;
#pragma unroll
    for (int nt = 0; nt < 8; ++nt) acc[nt][r] *= rinv;
  }
  __syncthreads();  // q/k reads done + implicit vmcnt(0) drains v stage

  // write P[w][u] bf16, swizzled
#pragma unroll
  for (int nt = 0; nt < 8; ++nt) {
    int u = nt * 16 + l15;
#pragma unroll
    for (int r = 0; r < 4; ++r) {
      int w = wid * 16 + 4 * g4 + r;
      int ch = (u >> 3) ^ (w & 15);
      P[w * 128 + ch * 8 + (u & 7)] = (u16)f2bf(acc[nt][r]);
    }
  }
  __syncthreads();

  // PV: D[m=d][n=w] = sum_u V[d][u] * P[w][u];  A=V, B=P (both natural-contig)
  const int mw = wid >> 2, nw = wid & 3;
  f32x4 pacc[2][2];
#pragma unroll
  for (int mi = 0; mi < 2; ++mi)
#pragma unroll
    for (int ni = 0; ni < 2; ++ni) { f32x4 zz = {0.f, 0.f, 0.f, 0.f}; pacc[mi][ni] = zz; }
  __builtin_amdgcn_s_setprio(1);
#pragma unroll
  for (int ks = 0; ks < 4; ++ks) {
    s16x8 av[2], bp[2];
#pragma unroll
    for (int mi = 0; mi < 2; ++mi) {
      int d = (mw * 2 + mi) * 16 + l15;
      av[mi] = *(const s16x8*)(vS + d * 128 + (((ks * 4 + g4) ^ (d & 15)) * 8));
    }
#pragma unroll
    for (int ni = 0; ni < 2; ++ni) {
      int w = (nw * 2 + ni) * 16 + l15;
      bp[ni] = *(const s16x8*)(P + w * 128 + (((ks * 4 + g4) ^ (w & 15)) * 8));
    }
#pragma unroll
    for (int mi = 0; mi < 2; ++mi)
#pragma unroll
      for (int ni = 0; ni < 2; ++ni)
        pacc[mi][ni] = MFMA(av[mi], bp[ni], pacc[mi][ni]);
  }
  __builtin_amdgcn_s_setprio(0);
  __syncthreads();  // all reads of P/vS done; smem free for epilogue tile

  // epilogue: pacc -> Tf[nj(seq)][d] (f32, stride 68), then coalesced stores
#pragma unroll
  for (int mi = 0; mi < 2; ++mi) {
    int d0 = (mw * 2 + mi) * 16 + 4 * g4;
#pragma unroll
    for (int ni = 0; ni < 2; ++ni) {
      int nj = (nw * 2 + ni) * 16 + l15;
      *(f32x4*)(Tf + nj * 68 + d0) = pacc[mi][ni];
    }
  }
  __syncthreads();
  // store pass: 128 rows x 64 u16 (128B/row); 8B per lane, 16 lanes per row
#pragma unroll
  for (int i = 0; i < 4; ++i) {
    int row = (tid >> 4) + i * 32;       // seq index
    int c4 = (tid & 15) * 4;             // d chunk (4 elems)
    f32x4 v4 = *(const f32x4*)(Tf + row * 68 + c4);
    long p = (MODE == 0) ? ((long)pos * 128 + row) : ((long)row * 128 + pos);
    u16* dst = outp + p * 512 + n * 64 + c4;
    s16x4 pk;
    if (MODE == 0) {
#pragma unroll
      for (int r = 0; r < 4; ++r) pk[r] = f2bf(v4[r]);
    } else {
      s16x4 old = *(const s16x4*)dst;
#pragma unroll
      for (int r = 0; r < 4; ++r) pk[r] = f2bf(bf2f(old[r]) + v4[r]);
    }
    *(s16x4*)dst = pk;
  }
}

// ---------------------------------------------------------------------------
extern "C" void kernel_launch(void* const* d_in, const int* in_sizes, int n_in,
                              void* d_out, int out_size, void* d_ws, size_t ws_size,
                              hipStream_t stream) {
  const float* x    = (const float*)d_in[0];
  const float* wqkv = (const float*)d_in[1];
  const float* bqkv = (const float*)d_in[2];
  const float* wout = (const float*)d_in[3];
  const float* bout = (const float*)d_in[4];
  float* out = (float*)d_out;

  char* ws = (char*)d_ws;
  size_t off = 0;
  auto alloc = [&](size_t bytes) { void* p = ws + off; off += (bytes + 255) & ~(size_t)255; return p; };
  u16* wqkv_bf = (u16*)alloc(1536L * 512 * 2);
  u16* wout_bf = (u16*)alloc(512L * 512 * 2);
  u16* xT      = (u16*)alloc(4L * 16384 * 512 * 2);   // [b][p][c]
  u16* qk_t    = (u16*)alloc(4L * 16384 * 1024 * 2);  // [b][p][o] o in 0..1023 (q,k)
  u16* v_buf   = (u16*)alloc(4L * 512 * 16384 * 2);   // [b][c][h][w]
  u16* vT      = (u16*)alloc(4L * 512 * 16384 * 2);   // [b][c][w][h]
  u16* attn_T  = (u16*)alloc(4L * 16384 * 512 * 2);   // [b][p][c]
  // total ws use ~386 MiB (ws = 512 MiB)

  cast_weights_kernel<<<256, 256, 0, stream>>>(wqkv, wqkv_bf, wout, wout_bf);
  // xT[b][p][c] = x[b][c][p]
  transpose_kernel<true><<<dim3(256, 8, 4), 256, 0, stream>>>(
      x, xT, 16384, 512, 512L * 16384, 16384L * 512);
  // qkv projection, all batches
  gemm_kernel<0><<<dim3(128, 12, 4), 256, 0, stream>>>(wqkv_bf, xT, bqkv, qk_t, v_buf, nullptr);
  // vT[b][c][w][h] = v[b][c][h][w]
  transpose_kernel<false><<<dim3(2, 2, 2048), 256, 0, stream>>>(v_buf, vT, 128, 128, 16384, 16384);
  // row attention (write), col attention (add)
  attn_kernel<0><<<dim3(4096), 512, 0, stream>>>(qk_t, v_buf, attn_T);
  attn_kernel<1><<<dim3(4096), 512, 0, stream>>>(qk_t, vT, attn_T);
  // out projection, all batches
  gemm_kernel<1><<<dim3(128, 4, 4), 256, 0, stream>>>(wout_bf, attn_T, bout, nullptr, nullptr, out);
}